// Round 9
// baseline (127.066 us; speedup 1.0000x reference)
//
#include <hip/hip_runtime.h>

// GCN aggregation: out = A @ embeds, A in COO with SORTED rows.
// N=100000, E=1.6M, D=64.
//
// Structure (R8 winner, 123.6us): prep (quantize + row_ptr, one
// grid-partitioned launch) then q8 gather with LDS edge staging:
// block = 16 rows (contiguous edge range), 256 threads coalesce-load
// col/val, premultiply scale[col], park (col<<6, w) in 4KB LDS; consume
// phase does ONE global VMEM (table gather) per edge.
//
// Ledger: R1 issue-count NULL; R2 row-pair regress; R3 atomics 2x regress;
// R4 wave-per-row 1.7x regress; R5 pw-pack -13us; R6 bf16 regress;
// R7 in-wave ping-pong regress (global col/val in pipeline, +VGPR);
// R8 LDS staging WIN (chain stage removed).
//
// R9: gather-level ping-pong on the R8 winner. LOADI(b+1) = LDS meta +
// issue 8 gathers, placed BEFORE COMP(b); compute waits counted vmcnt(8)
// so the next batch's gathers stay in flight. This is R7's idea with the
// objection removed: the pipelined stage no longer contains global
// col/val loads. Padding via clamped LDS idx + w=0 (off the global path).

#define GCN_D 64
#define CHUNK_E 512   // LDS edge capacity per block (4 KB); loop handles overflow

typedef float f4 __attribute__((ext_vector_type(4)));

__global__ __launch_bounds__(256) void prep_kernel(
    const float* __restrict__ embeds,
    unsigned char* __restrict__ ebq,    // N x 64 uint8 (offset-128)
    float* __restrict__ scale,          // N fp32 per-row scales
    int quant_blocks,
    const int* __restrict__ edge_row, int* __restrict__ row_ptr, int E, int N)
{
    if ((int)blockIdx.x < quant_blocks) {
        // 8 lanes per row, 8 dims (32 B) per lane.
        const int t   = blockIdx.x * blockDim.x + threadIdx.x;
        const int row = t >> 3;
        if (row >= N) return;
        const int l8 = (threadIdx.x & 7) * 8;

        const f4 a = __builtin_nontemporal_load(
            (const f4*)(embeds + (size_t)row * GCN_D + l8));
        const f4 b = __builtin_nontemporal_load(
            (const f4*)(embeds + (size_t)row * GCN_D + l8 + 4));

        float m = fmaxf(fmaxf(fmaxf(fabsf(a.x), fabsf(a.y)),
                              fmaxf(fabsf(a.z), fabsf(a.w))),
                        fmaxf(fmaxf(fabsf(b.x), fabsf(b.y)),
                              fmaxf(fabsf(b.z), fabsf(b.w))));
        m = fmaxf(m, __shfl_xor(m, 1));
        m = fmaxf(m, __shfl_xor(m, 2));
        m = fmaxf(m, __shfl_xor(m, 4));

        const float inv = (m > 0.f) ? 127.f / m : 0.f;
        const int q0 = (int)rintf(fminf(fmaxf(a.x * inv, -127.f), 127.f)) + 128;
        const int q1 = (int)rintf(fminf(fmaxf(a.y * inv, -127.f), 127.f)) + 128;
        const int q2 = (int)rintf(fminf(fmaxf(a.z * inv, -127.f), 127.f)) + 128;
        const int q3 = (int)rintf(fminf(fmaxf(a.w * inv, -127.f), 127.f)) + 128;
        const int q4 = (int)rintf(fminf(fmaxf(b.x * inv, -127.f), 127.f)) + 128;
        const int q5 = (int)rintf(fminf(fmaxf(b.y * inv, -127.f), 127.f)) + 128;
        const int q6 = (int)rintf(fminf(fmaxf(b.z * inv, -127.f), 127.f)) + 128;
        const int q7 = (int)rintf(fminf(fmaxf(b.w * inv, -127.f), 127.f)) + 128;

        unsigned int p0 =
            (unsigned)q0 | ((unsigned)q1 << 8) | ((unsigned)q2 << 16) | ((unsigned)q3 << 24);
        unsigned int p1 =
            (unsigned)q4 | ((unsigned)q5 << 8) | ((unsigned)q6 << 16) | ((unsigned)q7 << 24);

        unsigned int* dst = (unsigned int*)(ebq + (size_t)row * GCN_D + l8);
        dst[0] = p0;
        dst[1] = p1;
        if ((threadIdx.x & 7) == 0) scale[row] = m * (1.f / 127.f);
    } else {
        const int e = (blockIdx.x - quant_blocks) * blockDim.x + threadIdx.x;
        if (e >= E) return;
        const int r    = edge_row[e];
        const int prev = (e == 0) ? -1 : edge_row[e - 1];
        for (int k = prev + 1; k <= r; ++k) row_ptr[k] = e;
        if (e == E - 1)
            for (int k = r + 1; k <= N; ++k) row_ptr[k] = E;
    }
}

__device__ __forceinline__ void q8_fma4(unsigned int g, float w, f4& acc) {
    acc.x += w * (float)( g        & 0xffu);
    acc.y += w * (float)((g >> 8)  & 0xffu);
    acc.z += w * (float)((g >> 16) & 0xffu);
    acc.w += w * (float)( g >> 24);
}

__global__ __launch_bounds__(256) void gcn_row_q8_lds_kernel(
    const int* __restrict__ row_ptr,
    const int* __restrict__ edge_col,
    const float* __restrict__ edge_val,
    const unsigned char* __restrict__ ebq,
    const float* __restrict__ scale,
    float* __restrict__ out,
    int N)
{
    __shared__ int2 ls[CHUNK_E];             // (col<<6, w = val*scale[col])

    const int brow0 = blockIdx.x * 16;       // 16 rows per block
    const int row   = brow0 + (threadIdx.x >> 4);
    const int db    = (threadIdx.x & 15) * 4;   // dim base / byte offset
    const bool rv   = (row < N);

    const int p0 = rv ? row_ptr[row]     : 0;
    const int p1 = rv ? row_ptr[row + 1] : 0;

    const int rlast = (brow0 + 16 < N) ? (brow0 + 16) : N;
    const int r0 = row_ptr[brow0];
    const int r1 = row_ptr[rlast];

    f4    acc  = (f4)0.0f;
    float wsum = 0.0f;

    for (int cb = r0; cb < r1; cb += CHUNK_E) {
        const int ce = (cb + CHUNK_E < r1) ? (cb + CHUNK_E) : r1;

        __syncthreads();                     // protect LDS reuse across chunks
        // Cooperative coalesced stage: col/val stream + scale premultiply.
        // col pre-shifted by 6 (table row stride 64 B).
        for (int i = cb + (int)threadIdx.x; i < ce; i += 256) {
            const int c = edge_col[i];
            ls[i - cb] = make_int2(c << 6, __float_as_int(edge_val[i] * scale[c]));
        }
        __syncthreads();

        // Consume this row's slice: 8-edge batches, gather-level ping-pong.
        // LOADI(b+1) (LDS meta + issue gathers) precedes COMP(b), so batch
        // b's compute waits counted vmcnt while b+1's gathers fly.
        const int k0 = (p0 > cb) ? p0 : cb;
        const int ke = (p1 < ce) ? p1 : ce;
        if (ke > k0) {
            const int nb   = (ke - k0 + 7) >> 3;
            const int lmax = ce - cb - 1;

            unsigned gA[8], gB[8];
            float    wA[8], wB[8];

            auto LOADI = [&](int b, unsigned* g, float* w) {
                const int kb = k0 + b * 8;
                int coff[8];
                #pragma unroll
                for (int j = 0; j < 8; ++j) {
                    int idx = kb + j - cb;
                    idx = (idx > lmax) ? lmax : idx;       // in-bounds pad
                    const int2 t = ls[idx];
                    coff[j] = t.x;
                    w[j] = (kb + j < ke) ? __int_as_float(t.y) : 0.0f;
                }
                #pragma unroll
                for (int j = 0; j < 8; ++j)
                    g[j] = *(const unsigned*)(ebq + (size_t)(unsigned)coff[j] + db);
            };
            auto COMP = [&](const unsigned* g, const float* w) {
                #pragma unroll
                for (int j = 0; j < 8; ++j) {
                    q8_fma4(g[j], w[j], acc);
                    wsum += w[j];
                }
            };

            LOADI(0, gA, wA);
            int b = 1;
            for (; b + 1 < nb; b += 2) {
                LOADI(b, gB, wB);
                COMP(gA, wA);
                LOADI(b + 1, gA, wA);
                COMP(gB, wB);
            }
            if (b < nb) {
                LOADI(b, gB, wB);
                COMP(gA, wA);
                COMP(gB, wB);
            } else {
                COMP(gA, wA);
            }
        }
    }

    if (rv) {
        acc = acc - 128.0f * wsum;           // fold out offset-128 zero point
        __builtin_nontemporal_store(acc, (f4*)(out + (size_t)row * GCN_D + db));
    }
}

extern "C" void kernel_launch(void* const* d_in, const int* in_sizes, int n_in,
                              void* d_out, int out_size, void* d_ws, size_t ws_size,
                              hipStream_t stream) {
    const int*   edge_row = (const int*)d_in[0];
    const int*   edge_col = (const int*)d_in[1];
    const float* edge_val = (const float*)d_in[2];
    const float* embeds   = (const float*)d_in[3];
    float*       out      = (float*)d_out;

    const int E = in_sizes[0];
    const int N = out_size / GCN_D;

    // ws layout: row_ptr | scale | int8 table (256B-aligned sections)
    int* row_ptr = (int*)d_ws;
    const size_t sc_off = (((size_t)(N + 1) * 4) + 255) & ~(size_t)255;
    float* scale = (float*)((char*)d_ws + sc_off);
    const size_t q_off = ((sc_off + (size_t)N * 4) + 255) & ~(size_t)255;
    unsigned char* ebq = (unsigned char*)d_ws + q_off;

    const int quant_blocks = (N * 8 + 255) / 256;   // 8 lanes per row
    const int rp_blocks    = (E + 255) / 256;
    prep_kernel<<<quant_blocks + rp_blocks, 256, 0, stream>>>(
        embeds, ebq, scale, quant_blocks, edge_row, row_ptr, E, N);

    const int row_blocks = (N + 15) / 16;           // 16 rows (256 threads) per block
    gcn_row_q8_lds_kernel<<<row_blocks, 256, 0, stream>>>(
        row_ptr, edge_col, edge_val, ebq, scale, out, N);
}